// Round 20
// baseline (524.441 us; speedup 1.0000x reference)
//
#include <hip/hip_runtime.h>

#define NTOKEN 50257
#define NTOK_PAD 50304   // 1572 * 32
#define SB 1024
#define C_LOG2PI 235.2482644909f  // 0.5 * 256 * log(2*pi)

typedef __attribute__((ext_vector_type(8))) short bf16x8;
typedef __attribute__((ext_vector_type(4))) short s16x4;
typedef __attribute__((ext_vector_type(4))) float f32x4;
typedef float f32x4u __attribute__((ext_vector_type(4), aligned(4)));

#define MFMA16(a, b, c) __builtin_amdgcn_mfma_f32_16x16x32_bf16((a), (b), (c), 0, 0, 0)

__device__ __forceinline__ unsigned short f2bf(float f) {
  unsigned int u = __float_as_uint(f);
  u += 0x7fffu + ((u >> 16) & 1u);   // round-to-nearest-even
  return (unsigned short)(u >> 16);
}
__device__ __forceinline__ float bf2f(unsigned short s) {
  return __uint_as_float(((unsigned int)s) << 16);
}

// ---------------- workspace layout (bytes) ----------------
// Fragment-major layout MF[rowblk][s][lane] (16B frags):
//   frag holds M[rowblk*16 + (lane&15)][s*32 + (lane>>4)*8 .. +8] as bf16x8
//   byte offset = rowblk*8192 + s*1024 + lane*16 -> wave load is 1KB stream.
#define HBF_OFF  0u            // 64 rowblk * 8192 = 524288
#define ZBF_OFF  524288u       // 3144 rowblk * 8192 = 25755648 (fragment-major Z)
#define HN_OFF   26279936u     // 1024*4
#define CB_OFF   26284032u     // 50304*4
#define DM_OFF   26485248u     // 256*4
#define CV_OFF   26486272u     // 256*4
#define W1F_OFF  26487296u     // 16 rowblk * 8192 = 131072
#define W2F_OFF  26618368u     // 131072 (end = 26749440)

// ---------------- prep: fragment-major hbF/W1F/W2F + hnorm + dM/cvec ----------
// grid = 128 (hbF) + 32 (hnorm) + 32 (WF) + 64 (diag/cvec) = 256 blocks x 256
__global__ __launch_bounds__(256) void prep_all(
    const float* __restrict__ h, const float* __restrict__ W1x,
    const float* __restrict__ W2, const float* __restrict__ w1t,
    const float* __restrict__ b2, char* __restrict__ hbF,
    float* __restrict__ hnorm, char* __restrict__ W1F,
    char* __restrict__ W2F, float* __restrict__ dM,
    float* __restrict__ cvec) {
  const int bid = blockIdx.x;
  const int tid = threadIdx.x;
  if (bid < 128) {
    // ---- h -> fragment-major hbF ----
    int gid = bid * 256 + tid;           // 0..32767
    int rowblk = gid >> 9, rem = gid & 511;
    int s = rem >> 6, ln = rem & 63;
    int srow = rowblk * 16 + (ln & 15);
    int scol = s * 32 + (ln >> 4) * 8;
    const float4* p = (const float4*)&h[srow * 256 + scol];
    float4 x = p[0], y = p[1];
    float v[8] = {x.x, x.y, x.z, x.w, y.x, y.y, y.z, y.w};
    bf16x8 o;
    #pragma unroll
    for (int j = 0; j < 8; ++j) o[j] = (short)f2bf(v[j]);
    *(bf16x8*)(hbF + (size_t)gid * 16) = o;
  } else if (bid < 160) {
    // ---- h row norms ----
    int row = (bid - 128) * 32 + (tid >> 3);
    int c0 = (tid & 7) * 32;
    float ss = 0.f;
    #pragma unroll
    for (int g = 0; g < 4; ++g) {
      const float4* p = (const float4*)&h[row * 256 + c0 + g * 8];
      float4 x = p[0], y = p[1];
      ss += x.x * x.x + x.y * x.y + x.z * x.z + x.w * x.w;
      ss += y.x * y.x + y.y * y.y + y.z * y.z + y.w * y.w;
    }
    ss += __shfl_xor(ss, 1); ss += __shfl_xor(ss, 2); ss += __shfl_xor(ss, 4);
    if ((tid & 7) == 0) hnorm[row] = ss;
  } else if (bid < 192) {
    // ---- W1x, W2 -> fragment-major W1F/W2F ----
    int gid = (bid - 160) * 256 + tid;   // 0..8191
    int rowblk = gid >> 9, rem = gid & 511;
    int s = rem >> 6, ln = rem & 63;
    int srow = rowblk * 16 + (ln & 15);
    int scol = s * 32 + (ln >> 4) * 8;
    {
      const float4* p = (const float4*)&W1x[srow * 256 + scol];
      float4 x = p[0], y = p[1];
      float v[8] = {x.x, x.y, x.z, x.w, y.x, y.y, y.z, y.w};
      bf16x8 o;
      #pragma unroll
      for (int j = 0; j < 8; ++j) o[j] = (short)f2bf(v[j]);
      *(bf16x8*)(W1F + (size_t)gid * 16) = o;
    }
    {
      const float4* p = (const float4*)&W2[srow * 256 + scol];
      float4 x = p[0], y = p[1];
      float v[8] = {x.x, x.y, x.z, x.w, y.x, y.y, y.z, y.w};
      bf16x8 o;
      #pragma unroll
      for (int j = 0; j < 8; ++j) o[j] = (short)f2bf(v[j]);
      *(bf16x8*)(W2F + (size_t)gid * 16) = o;
    }
  } else {
    // ---- dM[j] = sum_i W1x[j,i]*W2[i,j]; cvec[j] = .5*(W1x[j,:]·b2 + w1t[j]) ----
    int j = (bid - 192) * 4 + (tid >> 6);
    int lane = tid & 63;
    float s = 0.f, s2 = 0.f;
    #pragma unroll
    for (int t = 0; t < 4; ++t) {
      int i = lane + t * 64;
      float w1 = W1x[j * 256 + i];
      s += w1 * W2[i * 256 + j];
      s2 += w1 * b2[i];
    }
    #pragma unroll
    for (int d = 1; d < 64; d <<= 1) {
      s += __shfl_xor(s, d);
      s2 += __shfl_xor(s2, d);
    }
    if (lane == 0) { dM[j] = s; cvec[j] = 0.5f * (s2 + w1t[j]); }
  }
}

// ---- 32x256 LDS tile (token rows, XOR-swizzled 16B groups) x fragment-major W
// acc[m][n] = MFMA16(Wfrag[m], Tfrag[n]) -> D[wcol][token]:
//   wcol = cb + m*16 + rg + r (contiguous in r), token = n*16 + l15.
__device__ __forceinline__ void mmT32(const short* T, const char* __restrict__ WF,
                                      int l15, int lane, int wv, f32x4 acc[4][2]) {
  const f32x4 vz = {0.f, 0.f, 0.f, 0.f};
  #pragma unroll
  for (int m = 0; m < 4; ++m)
    #pragma unroll
    for (int n = 0; n < 2; ++n) acc[m][n] = vz;
  const int kof = (lane >> 4) * 8;
  const char* wbase = WF + (size_t)wv * 4 * 8192 + lane * 16;
  #pragma unroll
  for (int s = 0; s < 8; ++s) {
    int ks = (s * 32 + kof) ^ ((l15 & 7) << 3);
    bf16x8 z[2];
    #pragma unroll
    for (int n = 0; n < 2; ++n)
      z[n] = *(const bf16x8*)&T[(n * 16 + l15) * 256 + ks];
    #pragma unroll
    for (int m = 0; m < 4; ++m) {
      bf16x8 w = *(const bf16x8*)(wbase + m * 8192 + s * 1024);  // 1KB stream
      #pragma unroll
      for (int n = 0; n < 2; ++n) acc[m][n] = MFMA16(w, z[n], acc[m][n]);
    }
  }
}

// ---------------- CNF: 32-token tile, z0 -> sp -> G in place ----------------
// Produces zbF (fragment-major bf16 Z) and cbias.
// (256,2): registers > waves for streamed operands (round-13 lesson).
__global__ __launch_bounds__(256, 2) void cnf4(
    const float* __restrict__ emb, const char* __restrict__ W1F,
    const char* __restrict__ W2F, const float* __restrict__ dM,
    const float* __restrict__ cvec, const float* __restrict__ b1,
    char* __restrict__ zbF, float* __restrict__ cbias) {
  __shared__ short zt[32 * 256];    // 16 KB: z0 -> sp -> G
  __shared__ float trs[4][32];
  __shared__ float znl[32];
  const int tid = threadIdx.x;
  const int lane = tid & 63, wv = tid >> 6;
  const int l15 = lane & 15, rg = (lane >> 4) * 4;
  const int cb = wv * 64;
  const int tokbase = blockIdx.x * 32;

  // ---- stage z0: slot-linear LDS writes (conflict-free), XOR folded into
  // the global read; row norms via 32-lane shfl ----
  #pragma unroll
  for (int k = 0; k < 4; ++k) {
    int o = tid + k * 256;
    int row = o >> 5, blk = o & 31;
    int g = (blk & 24) | ((blk & 7) ^ (row & 7));
    int gtok = tokbase + row;
    float v[8];
    if (gtok < NTOKEN) {
      const float4* p = (const float4*)&emb[(size_t)gtok * 256 + g * 8];
      float4 x = p[0], y = p[1];
      v[0] = x.x; v[1] = x.y; v[2] = x.z; v[3] = x.w;
      v[4] = y.x; v[5] = y.y; v[6] = y.z; v[7] = y.w;
    } else {
      #pragma unroll
      for (int j = 0; j < 8; ++j) v[j] = 0.f;
    }
    bf16x8 ob;
    float ss = 0.f;
    #pragma unroll
    for (int j = 0; j < 8; ++j) { ss += v[j] * v[j]; ob[j] = (short)f2bf(v[j]); }
    *(bf16x8*)((char*)zt + o * 16) = ob;
    ss += __shfl_xor(ss, 1); ss += __shfl_xor(ss, 2); ss += __shfl_xor(ss, 4);
    ss += __shfl_xor(ss, 8); ss += __shfl_xor(ss, 16);
    if ((tid & 31) == 0) znl[(tid >> 5) + k * 8] = ss;
  }
  __syncthreads();

  f32x4 acc[4][2];
  unsigned int p0a[4][2], p0b[4][2];   // pre0 packed 2xbf16 (16 VGPR)

  // ---- pass A: pre0^T = W1 x z0 ----
  mmT32(zt, W1F, l15, lane, wv, acc);

  // ---- zbF writeback: fragment-major, coalesced 16B/lane global stores.
  // frag p: rowblk = p>>9, s = (p>>6)&7, ln = p&63;
  // src token t = (p>>9)*16 + (p&15), group g = s*4 + ((p>>4)&3),
  // LDS slot = (g&24)|((g&7)^(t&7)). (z0 still intact in zt here.)
  #pragma unroll
  for (int k = 0; k < 4; ++k) {
    int p = k * 256 + tid;
    int s = (p >> 6) & 7;
    int t_local = ((p >> 9) << 4) + (p & 15);
    int g = s * 4 + ((p >> 4) & 3);
    int slot = (g & 24) | ((g & 7) ^ (t_local & 7));
    *(bf16x8*)(zbF + (size_t)tokbase * 512 + (size_t)p * 16) =
        *(const bf16x8*)((const char*)zt + t_local * 512 + slot * 16);
  }
  __syncthreads();   // all waves done reading z0 before sp overwrites
  {
    float p[2] = {0.f, 0.f};
    #pragma unroll
    for (int m = 0; m < 4; ++m) {
      f32x4 b1v = *(const f32x4*)&b1[cb + m * 16 + rg];
      f32x4 dmv = *(const f32x4*)&dM[cb + m * 16 + rg];
      #pragma unroll
      for (int n = 0; n < 2; ++n) {
        s16x4 spv;
        float pre[4];
        #pragma unroll
        for (int r = 0; r < 4; ++r) {
          pre[r] = acc[m][n][r] + b1v[r];
          float e = __expf(-fabsf(pre[r]));
          float rc = __fdividef(1.f, 1.f + e);
          p[n] += ((pre[r] >= 0.f) ? rc : e * rc) * dmv[r];
          spv[r] = (short)f2bf(fmaxf(pre[r], 0.f) + __logf(1.f + e));
        }
        p0a[m][n] = (unsigned int)f2bf(pre[0]) | ((unsigned int)f2bf(pre[1]) << 16);
        p0b[m][n] = (unsigned int)f2bf(pre[2]) | ((unsigned int)f2bf(pre[3]) << 16);
        int token = n * 16 + l15;
        int colb = (cb + m * 16 + rg) * 2;
        *(s16x4*)((char*)zt + token * 512 + (colb ^ ((token & 7) << 4))) = spv;
      }
    }
    #pragma unroll
    for (int n = 0; n < 2; ++n) {
      p[n] += __shfl_xor(p[n], 16);
      p[n] += __shfl_xor(p[n], 32);
    }
    if (lane < 16)
      #pragma unroll
      for (int n = 0; n < 2; ++n) trs[wv][n * 16 + l15] = p[n];
  }
  __syncthreads();

  // ---- pass B: G = sp @ W2^T -> zt ----
  mmT32(zt, W2F, l15, lane, wv, acc);
  __syncthreads();   // all waves done reading sp
  #pragma unroll
  for (int m = 0; m < 4; ++m)
    #pragma unroll
    for (int n = 0; n < 2; ++n) {
      s16x4 gv;
      #pragma unroll
      for (int r = 0; r < 4; ++r) gv[r] = (short)f2bf(acc[m][n][r]);
      int token = n * 16 + l15;
      int colb = (cb + m * 16 + rg) * 2;
      *(s16x4*)((char*)zt + token * 512 + (colb ^ ((token & 7) << 4))) = gv;
    }
  __syncthreads();

  // ---- pass C: H = G @ W1^T; pre1 = pre0 + 0.5*H + cvec; tr1 ----
  mmT32(zt, W1F, l15, lane, wv, acc);
  {
    float p[2] = {0.f, 0.f};
    #pragma unroll
    for (int m = 0; m < 4; ++m) {
      f32x4 cvv = *(const f32x4*)&cvec[cb + m * 16 + rg];
      f32x4 dmv = *(const f32x4*)&dM[cb + m * 16 + rg];
      #pragma unroll
      for (int n = 0; n < 2; ++n) {
        float pr0[4] = {bf2f((unsigned short)(p0a[m][n] & 0xffffu)),
                        bf2f((unsigned short)(p0a[m][n] >> 16)),
                        bf2f((unsigned short)(p0b[m][n] & 0xffffu)),
                        bf2f((unsigned short)(p0b[m][n] >> 16))};
        #pragma unroll
        for (int r = 0; r < 4; ++r) {
          float pre = pr0[r] + 0.5f * acc[m][n][r] + cvv[r];
          float e = __expf(-fabsf(pre));
          float rc = __fdividef(1.f, 1.f + e);
          p[n] += ((pre >= 0.f) ? rc : e * rc) * dmv[r];
        }
      }
    }
    #pragma unroll
    for (int n = 0; n < 2; ++n) {
      p[n] += __shfl_xor(p[n], 16);
      p[n] += __shfl_xor(p[n], 32);
    }
    if (lane < 16)
      #pragma unroll
      for (int n = 0; n < 2; ++n) trs[wv][n * 16 + l15] += p[n];
  }
  __syncthreads();

  if (tid < 32) {
    float t = trs[0][tid] + trs[1][tid] + trs[2][tid] + trs[3][tid];
    cbias[tokbase + tid] = -0.5f * znl[tid] - C_LOG2PI + 0.5f * t;
  }
}

// ---------------- big log-prob GEMM: patch-transpose epilogue ----------------
// Block: 256 h-rows x 64 tokens (4 waves x 64 rows). Both operands
// fragment-major 1KB wave-streams (round-11 win). Patch-transpose epilogue
// (round-19 win, -6.5us): each store covers 4 rows x 256 B contiguous.
// (256,8): kernel sits at exactly 64 VGPR / 18.4 KB LDS -> 8 blocks/CU fit;
// doubles resident waves to hide L2/L3 stream + store latency (round-17
// profile: Occ 37.7%, all pipes idle = TLP-starved).
// XCD scheme: x = bid&7; stripe = x>>1, tc = (x&1)*393 + bid>>3.
__global__ __launch_bounds__(256, 8) void logp_kernel(
    const char* __restrict__ hbF, const char* __restrict__ zbF,
    const float* __restrict__ hnorm, const float* __restrict__ cbias,
    float* __restrict__ out) {
  __shared__ float patch_all[4][16 * 72];   // 18432 B, wave-private patches
  const int bid = blockIdx.x;      // 3144 = 393 * 8
  const int x = bid & 7;
  const int stripe = x >> 1;
  const int tc = (x & 1) * 393 + (bid >> 3);
  const int tokbase = tc * 64;
  const int tid = threadIdx.x;
  const int lane = tid & 63, wv = tid >> 6;
  const int l15 = lane & 15, rg = (lane >> 4) * 4;

  f32x4 acc2[4][4];
  const f32x4 vz = {0.f, 0.f, 0.f, 0.f};
  #pragma unroll
  for (int n = 0; n < 4; ++n)
    #pragma unroll
    for (int m = 0; m < 4; ++m) acc2[n][m] = vz;

  const char* abase = hbF + (size_t)(stripe * 16 + wv * 4) * 8192 + lane * 16;
  const char* bbase = zbF + (size_t)tc * 4 * 8192 + lane * 16;
  #pragma unroll
  for (int s = 0; s < 8; ++s) {
    bf16x8 z[4];
    #pragma unroll
    for (int n = 0; n < 4; ++n)
      z[n] = *(const bf16x8*)(bbase + n * 8192 + s * 1024);    // 1KB stream
    #pragma unroll
    for (int m = 0; m < 4; ++m) {
      bf16x8 a = *(const bf16x8*)(abase + m * 8192 + s * 1024);  // 1KB stream
      #pragma unroll
      for (int n = 0; n < 4; ++n) acc2[n][m] = MFMA16(z[n], a, acc2[n][m]);
    }
  }

  // ---- patch-transpose stores ----
  float* patch = patch_all[wv];
  const int l4 = lane & 15, lr4 = lane >> 4;
  const int gt = tokbase + l4 * 4;
  f32x4 cb4 = *(const f32x4*)&cbias[gt];
  const int rowbase = stripe * 256 + wv * 64;
  #pragma unroll
  for (int m = 0; m < 4; ++m) {
    // write: lane owns (row l15, tokens n*16+rg..+3) -> 2-4 way aliasing
    #pragma unroll
    for (int n = 0; n < 4; ++n)
      *(f32x4*)&patch[l15 * 72 + n * 16 + rg] = acc2[n][m];
    asm volatile("s_waitcnt lgkmcnt(0)" ::: "memory");
    // read+store: 16 lanes span 64 contiguous tokens of one row;
    // each instruction = 4 rows x 256 B contiguous.
    #pragma unroll
    for (int q = 0; q < 4; ++q) {
      int lrow = q * 4 + lr4;
      int gr = rowbase + m * 16 + lrow;
      float hn = 0.5f * hnorm[gr];
      f32x4 v = *(const f32x4*)&patch[lrow * 72 + l4 * 4];
      #pragma unroll
      for (int r = 0; r < 4; ++r) v[r] += cb4[r] - hn;
      float* op = out + (size_t)gr * NTOKEN + gt;
      if (gt + 4 <= NTOKEN) {
        *(f32x4u*)op = v;
      } else {
        #pragma unroll
        for (int r = 0; r < 4; ++r)
          if (gt + r < NTOKEN) op[r] = v[r];
      }
    }
    asm volatile("s_waitcnt lgkmcnt(0)" ::: "memory");
  }
}

// ---------------- launcher ----------------
extern "C" void kernel_launch(void* const* d_in, const int* in_sizes, int n_in,
                              void* d_out, int out_size, void* d_ws, size_t ws_size,
                              hipStream_t stream) {
  const float* h   = (const float*)d_in[0];
  const float* emb = (const float*)d_in[1];
  const float* W1x = (const float*)d_in[2];
  const float* w1t = (const float*)d_in[3];
  const float* b1  = (const float*)d_in[4];
  const float* W2  = (const float*)d_in[5];
  const float* b2  = (const float*)d_in[6];
  float* out = (float*)d_out;

  char* ws = (char*)d_ws;
  char*  hbF   = ws + HBF_OFF;
  char*  zbF   = ws + ZBF_OFF;
  float* hnorm = (float*)(ws + HN_OFF);
  float* cbias = (float*)(ws + CB_OFF);
  float* dM    = (float*)(ws + DM_OFF);
  float* cvec  = (float*)(ws + CV_OFF);
  char*  W1F   = ws + W1F_OFF;
  char*  W2F   = ws + W2F_OFF;

  prep_all<<<256, 256, 0, stream>>>(h, W1x, W2, w1t, b2, hbF, hnorm, W1F, W2F,
                                    dM, cvec);
  cnf4<<<NTOK_PAD / 32, 256, 0, stream>>>(emb, W1F, W2F, dM, cvec, b1, zbF,
                                          cbias);
  logp_kernel<<<393 * 8, 256, 0, stream>>>(hbF, zbF, hnorm, cbias, out);
}

// Round 21
// 141.583 us; speedup vs baseline: 3.7041x; 3.7041x over previous
//
#include <hip/hip_runtime.h>

#define NTOKEN 50257
#define NTOK_PAD 50304   // 1572 * 32
#define SB 1024
#define C_LOG2PI 235.2482644909f  // 0.5 * 256 * log(2*pi)

typedef __attribute__((ext_vector_type(8))) short bf16x8;
typedef __attribute__((ext_vector_type(4))) short s16x4;
typedef __attribute__((ext_vector_type(4))) float f32x4;
typedef float f32x4u __attribute__((ext_vector_type(4), aligned(4)));

#define MFMA16(a, b, c) __builtin_amdgcn_mfma_f32_16x16x32_bf16((a), (b), (c), 0, 0, 0)

__device__ __forceinline__ unsigned short f2bf(float f) {
  unsigned int u = __float_as_uint(f);
  u += 0x7fffu + ((u >> 16) & 1u);   // round-to-nearest-even
  return (unsigned short)(u >> 16);
}
__device__ __forceinline__ float bf2f(unsigned short s) {
  return __uint_as_float(((unsigned int)s) << 16);
}

// ---------------- workspace layout (bytes) ----------------
// Fragment-major layout MF[rowblk][s][lane] (16B frags):
//   frag holds M[rowblk*16 + (lane&15)][s*32 + (lane>>4)*8 .. +8] as bf16x8
//   byte offset = rowblk*8192 + s*1024 + lane*16 -> wave load is 1KB stream.
#define HBF_OFF  0u            // 64 rowblk * 8192 = 524288
#define ZBF_OFF  524288u       // 3144 rowblk * 8192 = 25755648 (fragment-major Z)
#define HN_OFF   26279936u     // 1024*4
#define CB_OFF   26284032u     // 50304*4
#define DM_OFF   26485248u     // 256*4
#define CV_OFF   26486272u     // 256*4
#define W1F_OFF  26487296u     // 16 rowblk * 8192 = 131072
#define W2F_OFF  26618368u     // 131072 (end = 26749440)

// ---------------- prep: fragment-major hbF/W1F/W2F + hnorm + dM/cvec ----------
// grid = 128 (hbF) + 32 (hnorm) + 32 (WF) + 64 (diag/cvec) = 256 blocks x 256
__global__ __launch_bounds__(256) void prep_all(
    const float* __restrict__ h, const float* __restrict__ W1x,
    const float* __restrict__ W2, const float* __restrict__ w1t,
    const float* __restrict__ b2, char* __restrict__ hbF,
    float* __restrict__ hnorm, char* __restrict__ W1F,
    char* __restrict__ W2F, float* __restrict__ dM,
    float* __restrict__ cvec) {
  const int bid = blockIdx.x;
  const int tid = threadIdx.x;
  if (bid < 128) {
    // ---- h -> fragment-major hbF ----
    int gid = bid * 256 + tid;           // 0..32767
    int rowblk = gid >> 9, rem = gid & 511;
    int s = rem >> 6, ln = rem & 63;
    int srow = rowblk * 16 + (ln & 15);
    int scol = s * 32 + (ln >> 4) * 8;
    const float4* p = (const float4*)&h[srow * 256 + scol];
    float4 x = p[0], y = p[1];
    float v[8] = {x.x, x.y, x.z, x.w, y.x, y.y, y.z, y.w};
    bf16x8 o;
    #pragma unroll
    for (int j = 0; j < 8; ++j) o[j] = (short)f2bf(v[j]);
    *(bf16x8*)(hbF + (size_t)gid * 16) = o;
  } else if (bid < 160) {
    // ---- h row norms ----
    int row = (bid - 128) * 32 + (tid >> 3);
    int c0 = (tid & 7) * 32;
    float ss = 0.f;
    #pragma unroll
    for (int g = 0; g < 4; ++g) {
      const float4* p = (const float4*)&h[row * 256 + c0 + g * 8];
      float4 x = p[0], y = p[1];
      ss += x.x * x.x + x.y * x.y + x.z * x.z + x.w * x.w;
      ss += y.x * y.x + y.y * y.y + y.z * y.z + y.w * y.w;
    }
    ss += __shfl_xor(ss, 1); ss += __shfl_xor(ss, 2); ss += __shfl_xor(ss, 4);
    if ((tid & 7) == 0) hnorm[row] = ss;
  } else if (bid < 192) {
    // ---- W1x, W2 -> fragment-major W1F/W2F ----
    int gid = (bid - 160) * 256 + tid;   // 0..8191
    int rowblk = gid >> 9, rem = gid & 511;
    int s = rem >> 6, ln = rem & 63;
    int srow = rowblk * 16 + (ln & 15);
    int scol = s * 32 + (ln >> 4) * 8;
    {
      const float4* p = (const float4*)&W1x[srow * 256 + scol];
      float4 x = p[0], y = p[1];
      float v[8] = {x.x, x.y, x.z, x.w, y.x, y.y, y.z, y.w};
      bf16x8 o;
      #pragma unroll
      for (int j = 0; j < 8; ++j) o[j] = (short)f2bf(v[j]);
      *(bf16x8*)(W1F + (size_t)gid * 16) = o;
    }
    {
      const float4* p = (const float4*)&W2[srow * 256 + scol];
      float4 x = p[0], y = p[1];
      float v[8] = {x.x, x.y, x.z, x.w, y.x, y.y, y.z, y.w};
      bf16x8 o;
      #pragma unroll
      for (int j = 0; j < 8; ++j) o[j] = (short)f2bf(v[j]);
      *(bf16x8*)(W2F + (size_t)gid * 16) = o;
    }
  } else {
    // ---- dM[j] = sum_i W1x[j,i]*W2[i,j]; cvec[j] = .5*(W1x[j,:]·b2 + w1t[j]) ----
    int j = (bid - 192) * 4 + (tid >> 6);
    int lane = tid & 63;
    float s = 0.f, s2 = 0.f;
    #pragma unroll
    for (int t = 0; t < 4; ++t) {
      int i = lane + t * 64;
      float w1 = W1x[j * 256 + i];
      s += w1 * W2[i * 256 + j];
      s2 += w1 * b2[i];
    }
    #pragma unroll
    for (int d = 1; d < 64; d <<= 1) {
      s += __shfl_xor(s, d);
      s2 += __shfl_xor(s2, d);
    }
    if (lane == 0) { dM[j] = s; cvec[j] = 0.5f * (s2 + w1t[j]); }
  }
}

// ---- 32x256 LDS tile (token rows, XOR-swizzled 16B groups) x fragment-major W
// acc[m][n] = MFMA16(Wfrag[m], Tfrag[n]) -> D[wcol][token]:
//   wcol = cb + m*16 + rg + r (contiguous in r), token = n*16 + l15.
__device__ __forceinline__ void mmT32(const short* T, const char* __restrict__ WF,
                                      int l15, int lane, int wv, f32x4 acc[4][2]) {
  const f32x4 vz = {0.f, 0.f, 0.f, 0.f};
  #pragma unroll
  for (int m = 0; m < 4; ++m)
    #pragma unroll
    for (int n = 0; n < 2; ++n) acc[m][n] = vz;
  const int kof = (lane >> 4) * 8;
  const char* wbase = WF + (size_t)wv * 4 * 8192 + lane * 16;
  #pragma unroll
  for (int s = 0; s < 8; ++s) {
    int ks = (s * 32 + kof) ^ ((l15 & 7) << 3);
    bf16x8 z[2];
    #pragma unroll
    for (int n = 0; n < 2; ++n)
      z[n] = *(const bf16x8*)&T[(n * 16 + l15) * 256 + ks];
    #pragma unroll
    for (int m = 0; m < 4; ++m) {
      bf16x8 w = *(const bf16x8*)(wbase + m * 8192 + s * 1024);  // 1KB stream
      #pragma unroll
      for (int n = 0; n < 2; ++n) acc[m][n] = MFMA16(w, z[n], acc[m][n]);
    }
  }
}

// ---------------- CNF: 32-token tile, z0 -> sp -> G in place ----------------
// Produces zbF (fragment-major bf16 Z) and cbias.
// (256,2): registers > waves for streamed operands (round-13/20 lesson).
__global__ __launch_bounds__(256, 2) void cnf4(
    const float* __restrict__ emb, const char* __restrict__ W1F,
    const char* __restrict__ W2F, const float* __restrict__ dM,
    const float* __restrict__ cvec, const float* __restrict__ b1,
    char* __restrict__ zbF, float* __restrict__ cbias) {
  __shared__ short zt[32 * 256];    // 16 KB: z0 -> sp -> G
  __shared__ float trs[4][32];
  __shared__ float znl[32];
  const int tid = threadIdx.x;
  const int lane = tid & 63, wv = tid >> 6;
  const int l15 = lane & 15, rg = (lane >> 4) * 4;
  const int cb = wv * 64;
  const int tokbase = blockIdx.x * 32;

  // ---- stage z0: slot-linear LDS writes (conflict-free), XOR folded into
  // the global read; row norms via 32-lane shfl ----
  #pragma unroll
  for (int k = 0; k < 4; ++k) {
    int o = tid + k * 256;
    int row = o >> 5, blk = o & 31;
    int g = (blk & 24) | ((blk & 7) ^ (row & 7));
    int gtok = tokbase + row;
    float v[8];
    if (gtok < NTOKEN) {
      const float4* p = (const float4*)&emb[(size_t)gtok * 256 + g * 8];
      float4 x = p[0], y = p[1];
      v[0] = x.x; v[1] = x.y; v[2] = x.z; v[3] = x.w;
      v[4] = y.x; v[5] = y.y; v[6] = y.z; v[7] = y.w;
    } else {
      #pragma unroll
      for (int j = 0; j < 8; ++j) v[j] = 0.f;
    }
    bf16x8 ob;
    float ss = 0.f;
    #pragma unroll
    for (int j = 0; j < 8; ++j) { ss += v[j] * v[j]; ob[j] = (short)f2bf(v[j]); }
    *(bf16x8*)((char*)zt + o * 16) = ob;
    ss += __shfl_xor(ss, 1); ss += __shfl_xor(ss, 2); ss += __shfl_xor(ss, 4);
    ss += __shfl_xor(ss, 8); ss += __shfl_xor(ss, 16);
    if ((tid & 31) == 0) znl[(tid >> 5) + k * 8] = ss;
  }
  __syncthreads();

  f32x4 acc[4][2];
  unsigned int p0a[4][2], p0b[4][2];   // pre0 packed 2xbf16 (16 VGPR)

  // ---- pass A: pre0^T = W1 x z0 ----
  mmT32(zt, W1F, l15, lane, wv, acc);

  // ---- zbF writeback: fragment-major, coalesced 16B/lane global stores.
  // frag p: rowblk = p>>9, s = (p>>6)&7, ln = p&63;
  // src token t = (p>>9)*16 + (p&15), group g = s*4 + ((p>>4)&3),
  // LDS slot = (g&24)|((g&7)^(t&7)). (z0 still intact in zt here.)
  #pragma unroll
  for (int k = 0; k < 4; ++k) {
    int p = k * 256 + tid;
    int s = (p >> 6) & 7;
    int t_local = ((p >> 9) << 4) + (p & 15);
    int g = s * 4 + ((p >> 4) & 3);
    int slot = (g & 24) | ((g & 7) ^ (t_local & 7));
    *(bf16x8*)(zbF + (size_t)tokbase * 512 + (size_t)p * 16) =
        *(const bf16x8*)((const char*)zt + t_local * 512 + slot * 16);
  }
  __syncthreads();   // all waves done reading z0 before sp overwrites
  {
    float p[2] = {0.f, 0.f};
    #pragma unroll
    for (int m = 0; m < 4; ++m) {
      f32x4 b1v = *(const f32x4*)&b1[cb + m * 16 + rg];
      f32x4 dmv = *(const f32x4*)&dM[cb + m * 16 + rg];
      #pragma unroll
      for (int n = 0; n < 2; ++n) {
        s16x4 spv;
        float pre[4];
        #pragma unroll
        for (int r = 0; r < 4; ++r) {
          pre[r] = acc[m][n][r] + b1v[r];
          float e = __expf(-fabsf(pre[r]));
          float rc = __fdividef(1.f, 1.f + e);
          p[n] += ((pre[r] >= 0.f) ? rc : e * rc) * dmv[r];
          spv[r] = (short)f2bf(fmaxf(pre[r], 0.f) + __logf(1.f + e));
        }
        p0a[m][n] = (unsigned int)f2bf(pre[0]) | ((unsigned int)f2bf(pre[1]) << 16);
        p0b[m][n] = (unsigned int)f2bf(pre[2]) | ((unsigned int)f2bf(pre[3]) << 16);
        int token = n * 16 + l15;
        int colb = (cb + m * 16 + rg) * 2;
        *(s16x4*)((char*)zt + token * 512 + (colb ^ ((token & 7) << 4))) = spv;
      }
    }
    #pragma unroll
    for (int n = 0; n < 2; ++n) {
      p[n] += __shfl_xor(p[n], 16);
      p[n] += __shfl_xor(p[n], 32);
    }
    if (lane < 16)
      #pragma unroll
      for (int n = 0; n < 2; ++n) trs[wv][n * 16 + l15] = p[n];
  }
  __syncthreads();

  // ---- pass B: G = sp @ W2^T -> zt ----
  mmT32(zt, W2F, l15, lane, wv, acc);
  __syncthreads();   // all waves done reading sp
  #pragma unroll
  for (int m = 0; m < 4; ++m)
    #pragma unroll
    for (int n = 0; n < 2; ++n) {
      s16x4 gv;
      #pragma unroll
      for (int r = 0; r < 4; ++r) gv[r] = (short)f2bf(acc[m][n][r]);
      int token = n * 16 + l15;
      int colb = (cb + m * 16 + rg) * 2;
      *(s16x4*)((char*)zt + token * 512 + (colb ^ ((token & 7) << 4))) = gv;
    }
  __syncthreads();

  // ---- pass C: H = G @ W1^T; pre1 = pre0 + 0.5*H + cvec; tr1 ----
  mmT32(zt, W1F, l15, lane, wv, acc);
  {
    float p[2] = {0.f, 0.f};
    #pragma unroll
    for (int m = 0; m < 4; ++m) {
      f32x4 cvv = *(const f32x4*)&cvec[cb + m * 16 + rg];
      f32x4 dmv = *(const f32x4*)&dM[cb + m * 16 + rg];
      #pragma unroll
      for (int n = 0; n < 2; ++n) {
        float pr0[4] = {bf2f((unsigned short)(p0a[m][n] & 0xffffu)),
                        bf2f((unsigned short)(p0a[m][n] >> 16)),
                        bf2f((unsigned short)(p0b[m][n] & 0xffffu)),
                        bf2f((unsigned short)(p0b[m][n] >> 16))};
        #pragma unroll
        for (int r = 0; r < 4; ++r) {
          float pre = pr0[r] + 0.5f * acc[m][n][r] + cvv[r];
          float e = __expf(-fabsf(pre));
          float rc = __fdividef(1.f, 1.f + e);
          p[n] += ((pre >= 0.f) ? rc : e * rc) * dmv[r];
        }
      }
    }
    #pragma unroll
    for (int n = 0; n < 2; ++n) {
      p[n] += __shfl_xor(p[n], 16);
      p[n] += __shfl_xor(p[n], 32);
    }
    if (lane < 16)
      #pragma unroll
      for (int n = 0; n < 2; ++n) trs[wv][n * 16 + l15] += p[n];
  }
  __syncthreads();

  if (tid < 32) {
    float t = trs[0][tid] + trs[1][tid] + trs[2][tid] + trs[3][tid];
    cbias[tokbase + tid] = -0.5f * znl[tid] - C_LOG2PI + 0.5f * t;
  }
}

// ---------------- big log-prob GEMM: patch-transpose epilogue ----------------
// Block: 256 h-rows x 64 tokens (4 waves x 64 rows). Both operands
// fragment-major 1KB wave-streams (round-11 win). Patch-transpose epilogue
// (round-19 win): each store covers 4 rows x 256 B contiguous. (256,4):
// 64 VGPR, no spills — (256,8) forced VGPR=32 and spilled acc to scratch
// (round-20: WRITE 1.39 GB, 465 us). Registers > waves.
// XCD scheme: x = bid&7; stripe = x>>1, tc = (x&1)*393 + bid>>3.
__global__ __launch_bounds__(256, 4) void logp_kernel(
    const char* __restrict__ hbF, const char* __restrict__ zbF,
    const float* __restrict__ hnorm, const float* __restrict__ cbias,
    float* __restrict__ out) {
  __shared__ float patch_all[4][16 * 72];   // 18432 B, wave-private patches
  const int bid = blockIdx.x;      // 3144 = 393 * 8
  const int x = bid & 7;
  const int stripe = x >> 1;
  const int tc = (x & 1) * 393 + (bid >> 3);
  const int tokbase = tc * 64;
  const int tid = threadIdx.x;
  const int lane = tid & 63, wv = tid >> 6;
  const int l15 = lane & 15, rg = (lane >> 4) * 4;

  f32x4 acc2[4][4];
  const f32x4 vz = {0.f, 0.f, 0.f, 0.f};
  #pragma unroll
  for (int n = 0; n < 4; ++n)
    #pragma unroll
    for (int m = 0; m < 4; ++m) acc2[n][m] = vz;

  const char* abase = hbF + (size_t)(stripe * 16 + wv * 4) * 8192 + lane * 16;
  const char* bbase = zbF + (size_t)tc * 4 * 8192 + lane * 16;
  #pragma unroll
  for (int s = 0; s < 8; ++s) {
    bf16x8 z[4];
    #pragma unroll
    for (int n = 0; n < 4; ++n)
      z[n] = *(const bf16x8*)(bbase + n * 8192 + s * 1024);    // 1KB stream
    #pragma unroll
    for (int m = 0; m < 4; ++m) {
      bf16x8 a = *(const bf16x8*)(abase + m * 8192 + s * 1024);  // 1KB stream
      #pragma unroll
      for (int n = 0; n < 4; ++n) acc2[n][m] = MFMA16(z[n], a, acc2[n][m]);
    }
  }

  // ---- patch-transpose stores ----
  float* patch = patch_all[wv];
  const int l4 = lane & 15, lr4 = lane >> 4;
  const int gt = tokbase + l4 * 4;
  f32x4 cb4 = *(const f32x4*)&cbias[gt];
  const int rowbase = stripe * 256 + wv * 64;
  #pragma unroll
  for (int m = 0; m < 4; ++m) {
    // write: lane owns (row l15, tokens n*16+rg..+3) -> 2-4 way aliasing
    #pragma unroll
    for (int n = 0; n < 4; ++n)
      *(f32x4*)&patch[l15 * 72 + n * 16 + rg] = acc2[n][m];
    asm volatile("s_waitcnt lgkmcnt(0)" ::: "memory");
    // read+store: 16 lanes span 64 contiguous tokens of one row;
    // each instruction = 4 rows x 256 B contiguous.
    #pragma unroll
    for (int q = 0; q < 4; ++q) {
      int lrow = q * 4 + lr4;
      int gr = rowbase + m * 16 + lrow;
      float hn = 0.5f * hnorm[gr];
      f32x4 v = *(const f32x4*)&patch[lrow * 72 + l4 * 4];
      #pragma unroll
      for (int r = 0; r < 4; ++r) v[r] += cb4[r] - hn;
      float* op = out + (size_t)gr * NTOKEN + gt;
      if (gt + 4 <= NTOKEN) {
        *(f32x4u*)op = v;
      } else {
        #pragma unroll
        for (int r = 0; r < 4; ++r)
          if (gt + r < NTOKEN) op[r] = v[r];
      }
    }
    asm volatile("s_waitcnt lgkmcnt(0)" ::: "memory");
  }
}

// ---------------- launcher ----------------
extern "C" void kernel_launch(void* const* d_in, const int* in_sizes, int n_in,
                              void* d_out, int out_size, void* d_ws, size_t ws_size,
                              hipStream_t stream) {
  const float* h   = (const float*)d_in[0];
  const float* emb = (const float*)d_in[1];
  const float* W1x = (const float*)d_in[2];
  const float* w1t = (const float*)d_in[3];
  const float* b1  = (const float*)d_in[4];
  const float* W2  = (const float*)d_in[5];
  const float* b2  = (const float*)d_in[6];
  float* out = (float*)d_out;

  char* ws = (char*)d_ws;
  char*  hbF   = ws + HBF_OFF;
  char*  zbF   = ws + ZBF_OFF;
  float* hnorm = (float*)(ws + HN_OFF);
  float* cbias = (float*)(ws + CB_OFF);
  float* dM    = (float*)(ws + DM_OFF);
  float* cvec  = (float*)(ws + CV_OFF);
  char*  W1F   = ws + W1F_OFF;
  char*  W2F   = ws + W2F_OFF;

  prep_all<<<256, 256, 0, stream>>>(h, W1x, W2, w1t, b2, hbF, hnorm, W1F, W2F,
                                    dM, cvec);
  cnf4<<<NTOK_PAD / 32, 256, 0, stream>>>(emb, W1F, W2F, dM, cvec, b1, zbF,
                                          cbias);
  logp_kernel<<<393 * 8, 256, 0, stream>>>(hbF, zbF, hnorm, cbias, out);
}